// Round 11
// baseline (217.910 us; speedup 1.0000x reference)
//
#include <hip/hip_runtime.h>
#include <cstdint>
#include <cstddef>

// Problem shape (fixed by setup_inputs): B=8, S=2048, D=512. All tensors f32.
#define BATCH 8
#define SEQ   2048
#define DDIM  512
#define NROW  (BATCH*SEQ)          // 16384 token rows
#define KPACK (DDIM/4)             // 128 packed int32 per row
#define EPSQ  1e-5f
#define FSCALE 0.35355339059327373f  // 8 ** -0.5

typedef _Float16 half8 __attribute__((ext_vector_type(8)));
typedef _Float16 half4 __attribute__((ext_vector_type(4)));
typedef float    f32x4 __attribute__((ext_vector_type(4)));
typedef int      i32x4 __attribute__((ext_vector_type(4)));

// Workspace layout (bytes)
static constexpr size_t OFF_M   = 0;                                   // 3 floats abs-sum
static constexpr size_t OFF_WP  = 256;                                 // 3*512*128 int32 (col-major)
static constexpr size_t OFF_XQ  = OFF_WP + (size_t)3*KPACK*DDIM*4;     // 16384*128 int32
static constexpr size_t OFF_SX  = OFF_XQ + (size_t)NROW*KPACK*4;       // 16384 f32
static constexpr size_t OFF_QKV = OFF_SX + (size_t)NROW*4;             // 3*16384*512 f16
static constexpr size_t OFF_PO  = OFF_QKV + (size_t)3*NROW*DDIM*2;     // 512 slots * 64 * 512 f16 (region sized f32)
static constexpr size_t OFF_PM  = OFF_PO + (size_t)512*64*512*4;       // 512*64 f32 m
static constexpr size_t OFF_PL  = OFF_PM + (size_t)512*64*4;           // 512*64 f32 l

// raw-barrier schedule primitives (m201-validated pattern: counted vmcnt +
// lgkmcnt-only barriers; no vmcnt(0) drain in the steady-state loop)
#define VM8()   asm volatile("s_waitcnt vmcnt(8)" ::: "memory")
#define VM0()   asm volatile("s_waitcnt vmcnt(0)" ::: "memory")
#define LGKM0() asm volatile("s_waitcnt lgkmcnt(0)" ::: "memory")
#define BAR()   __builtin_amdgcn_s_barrier()

__device__ __forceinline__ int q8(float v, float s) {
  int i = (int)rintf(v * s);
  i = i < -128 ? -128 : (i > 127 ? 127 : i);
  return i & 0xff;
}

// async global->LDS DMA, 16B per lane; lds dest = wave-uniform base + lane*16
__device__ __forceinline__ void gld_lds16(const _Float16* g, _Float16* l) {
  __builtin_amdgcn_global_load_lds(
      (const __attribute__((address_space(1))) void*)g,
      (__attribute__((address_space(3))) void*)l, 16, 0, 0);
}

// ---------------------------------------------------------------------------
// 1. FUSED prep: blocks 0..95 = weight abs-sum; blocks 96..4191 = per-token
//    int8 absmax quantization. (round-10 exact — bench-verified)
// ---------------------------------------------------------------------------
__global__ __launch_bounds__(256) void prep_kernel(
    const float* __restrict__ Wq, const float* __restrict__ Wk,
    const float* __restrict__ Wv, float* __restrict__ mw,
    const float* __restrict__ x, int* __restrict__ xq,
    float* __restrict__ sx) {
  if (blockIdx.x < 96) {
    const int mat = blockIdx.x >> 5;
    const int bx  = blockIdx.x & 31;
    const float* W = mat == 0 ? Wq : (mat == 1 ? Wk : Wv);
    __shared__ float red[256];
    const float4* p = (const float4*)(W + bx * 8192);
    float s = 0.f;
    #pragma unroll
    for (int i = 0; i < 8; i++) {
      float4 a = p[i * 256 + threadIdx.x];
      s += fabsf(a.x) + fabsf(a.y) + fabsf(a.z) + fabsf(a.w);
    }
    red[threadIdx.x] = s;
    __syncthreads();
    for (int w = 128; w > 0; w >>= 1) {
      if ((int)threadIdx.x < w) red[threadIdx.x] += red[threadIdx.x + w];
      __syncthreads();
    }
    if (threadIdx.x == 0) atomicAdd(&mw[mat], red[0]);
  } else {
    int wid = threadIdx.x >> 6, lane = threadIdx.x & 63;
    int row = (blockIdx.x - 96) * 4 + wid;
    const float* xr = x + (size_t)row * DDIM;
    float4 a = ((const float4*)xr)[lane];
    float4 b = ((const float4*)xr)[64 + lane];
    float amax = fmaxf(fmaxf(fmaxf(fabsf(a.x), fabsf(a.y)), fmaxf(fabsf(a.z), fabsf(a.w))),
                       fmaxf(fmaxf(fabsf(b.x), fabsf(b.y)), fmaxf(fabsf(b.z), fabsf(b.w))));
    for (int off = 32; off > 0; off >>= 1) amax = fmaxf(amax, __shfl_xor(amax, off, 64));
    float aa = fmaxf(amax, EPSQ);
    float scale = 127.0f / aa;
    int p0 = q8(a.x, scale) | (q8(a.y, scale) << 8) | (q8(a.z, scale) << 16) | (q8(a.w, scale) << 24);
    int p1 = q8(b.x, scale) | (q8(b.y, scale) << 8) | (q8(b.z, scale) << 16) | (q8(b.w, scale) << 24);
    xq[(size_t)row * KPACK + lane]      = p0;
    xq[(size_t)row * KPACK + 64 + lane] = p1;
    if (lane == 0) sx[row] = aa * (1.0f / 127.0f);
  }
}

// ---------------------------------------------------------------------------
// 2. ternary-quantize weights, packed COL-major. (bench-verified)
// ---------------------------------------------------------------------------
__global__ __launch_bounds__(256) void wquant_kernel(
    const float* __restrict__ Wq, const float* __restrict__ Wk,
    const float* __restrict__ Wv, const float* __restrict__ mw,
    int* __restrict__ wp) {
  int idx = blockIdx.x * 256 + threadIdx.x;
  int mat = idx >> 16;
  int local = idx & 0xFFFF;
  int o  = local >> 7;
  int k4 = local & 127;
  const float* W = mat == 0 ? Wq : (mat == 1 ? Wk : Wv);
  float mean = mw[mat] * (1.0f / 262144.0f);
  float scale = 1.0f / fmaxf(mean, EPSQ);
  float4 w4 = *(const float4*)(W + (size_t)o * DDIM + k4 * 4);
  int t0 = (int)rintf(w4.x * scale); t0 = t0 < -1 ? -1 : (t0 > 1 ? 1 : t0);
  int t1 = (int)rintf(w4.y * scale); t1 = t1 < -1 ? -1 : (t1 > 1 ? 1 : t1);
  int t2 = (int)rintf(w4.z * scale); t2 = t2 < -1 ? -1 : (t2 > 1 ? 1 : t2);
  int t3 = (int)rintf(w4.w * scale); t3 = t3 < -1 ? -1 : (t3 > 1 ? 1 : t3);
  int packed = (t0 & 0xff) | ((t1 & 0xff) << 8) | ((t2 & 0xff) << 16) | ((t3 & 0xff) << 24);
  wp[((size_t)mat * DDIM + o) * KPACK + k4] = packed;
}

// ---------------------------------------------------------------------------
// 3. int8 x ternary GEMM via i8 MFMA. grid (256, 3). (round-6 exact)
// ---------------------------------------------------------------------------
__global__ __launch_bounds__(256, 2) void qkv_gemm_kernel(
    const int* __restrict__ xq, const int* __restrict__ wp,
    const float* __restrict__ sx, const float* __restrict__ mw,
    _Float16* __restrict__ qkv) {
  __shared__ __align__(16) int xs[64][132];
  __shared__ __align__(16) int bs[64][132];
  __shared__ float sxs[64];

  const int tid  = threadIdx.x;
  const int w    = tid >> 6;
  const int lane = tid & 63;
  const int quad = lane >> 4;
  const int col  = lane & 15;

  const int r0g = blockIdx.x * 64;
  const int mat = blockIdx.y;

  {
    const i32x4* src = (const i32x4*)(xq + (size_t)r0g * KPACK);
    #pragma unroll
    for (int i = 0; i < 8; i++) {
      int e = i * 256 + tid;
      int row = e >> 5, u = e & 31;
      *(i32x4*)&xs[row][u * 4] = src[e];
    }
  }
  if (tid < 64) sxs[tid] = sx[r0g + tid];

  const float mval = fmaxf(mw[mat] * (1.0f / 262144.0f), EPSQ);

  i32x4 breg[8];
  {
    const i32x4* src = (const i32x4*)(wp + (size_t)mat * DDIM * KPACK);
    #pragma unroll
    for (int i = 0; i < 8; i++) breg[i] = src[i * 256 + tid];
  }

  for (int nb = 0; nb < 8; nb++) {
    const int n0 = nb * 64;
    __syncthreads();
    #pragma unroll
    for (int i = 0; i < 8; i++) {
      int e = i * 256 + tid;
      int c = e >> 5, u = e & 31;
      *(i32x4*)&bs[c][u * 4] = breg[i];
    }
    __syncthreads();
    if (nb + 1 < 8) {
      const i32x4* src = (const i32x4*)(wp + ((size_t)mat * DDIM + n0 + 64) * KPACK);
      #pragma unroll
      for (int i = 0; i < 8; i++) breg[i] = src[i * 256 + tid];
    }

    i32x4 acc[4];
    #pragma unroll
    for (int rt = 0; rt < 4; rt++) acc[rt] = (i32x4)(0);

    #pragma unroll
    for (int s = 0; s < 8; s++) {
      i32x4 bf = *(const i32x4*)&bs[w * 16 + col][s * 16 + quad * 4];
      #pragma unroll
      for (int rt = 0; rt < 4; rt++) {
        i32x4 af = *(const i32x4*)&xs[rt * 16 + col][s * 16 + quad * 4];
        acc[rt] = __builtin_amdgcn_mfma_i32_16x16x64_i8(af, bf, acc[rt], 0, 0, 0);
      }
    }

    const int nw = n0 + w * 16 + col;

    if (mat < 2) {
      _Float16* outb = qkv + (size_t)mat * NROW * DDIM;
      #pragma unroll
      for (int rt = 0; rt < 4; rt++) {
        #pragma unroll
        for (int reg = 0; reg < 4; reg++) {
          int rowl = rt * 16 + quad * 4 + reg;
          outb[(size_t)(r0g + rowl) * DDIM + nw] =
              (_Float16)((float)acc[rt][reg] * sxs[rowl] * mval);
        }
      }
    } else {
      _Float16* vT = qkv + (size_t)2 * NROW * DDIM;
      #pragma unroll
      for (int rt = 0; rt < 4; rt++) {
        half4 hv;
        #pragma unroll
        for (int reg = 0; reg < 4; reg++) {
          int rowl = rt * 16 + quad * 4 + reg;
          hv[reg] = (_Float16)((float)acc[rt][reg] * sxs[rowl] * mval);
        }
        int r = r0g + rt * 16 + quad * 4;
        int b = r >> 11, kt = (r & 2047) >> 5, kin = r & 31;
        *(half4*)(vT + ((((size_t)b * 64 + kt) * 512 + nw) * 32 + kin)) = hv;
      }
    }
  }
}

// ---------------------------------------------------------------------------
// 4. f16 MFMA flash attention, ROUND 11: round-1 bench-verified inner code
//    (QBLK=64, 8 waves, grid 256 = 1 block/CU, 2-phase complementary pairing,
//    dbuf K+V) with the COUNTED-VMCNT raw-barrier schedule (T3/T4, m201
//    pattern): DMA(t+1) issued at loop top, waited with vmcnt(8) one full
//    tile later; B/C/D barriers use lgkmcnt(0) only — no vmcnt(0) drain in
//    the steady-state loop. NO device-scope fences (rounds 5/8 lesson).
// ---------------------------------------------------------------------------
__global__ __launch_bounds__(512, 2) void flash_kernel(
    const _Float16* __restrict__ q, const _Float16* __restrict__ k,
    const _Float16* __restrict__ vT, _Float16* __restrict__ po,
    float* __restrict__ pm, float* __restrict__ pl) {
  __shared__ __align__(16) _Float16 Ksh[2][32][520];  // 66,560 B
  __shared__ __align__(16) _Float16 VtL[2][512][32];  // 65,536 B
  __shared__ __align__(16) float    PsS[64 * 33];     //  8,448 B
  __shared__ __align__(16) _Float16 Pf[64 * 40];      //  5,120 B
  __shared__ float alpha_l[64];                       //    256 B
  // total 145,920 B -> 1 block/CU (8 waves)

  const int tid  = threadIdx.x;
  const int w    = tid >> 6;        // 0..7
  const int lane = tid & 63;
  const int quad = lane >> 4;
  const int col  = lane & 15;
  const int rt   = w & 3;           // score row-tile
  const int kh   = w >> 2;          // score key-half
  const int smrow = tid >> 3;       // softmax row 0..63
  const int sme   = tid & 7;        // softmax key group 0..7
  const int d0  = w * 64;           // PV dim slice

  const int vrl = lane >> 2;        // V-DMA row-in-group 0..15
  const int vu  = lane & 3;         // V-DMA 16B unit 0..3

  const int bb = blockIdx.x & 7;    // batch == XCD id (L2 pinning)
  const int qi = blockIdx.x >> 3;   // 0..31

  for (int ph = 0; ph < 2; ph++) {
    const int qt = ph ? (31 - qi) : qi;
    const int h  = ph;              // key-tile parity
    const int slot = (qt * 8 + bb) * 2 + h;
    const int nT = qt + 1;          // tiles in this slot

    const int qrow0 = qt * 64;
    const size_t bbase = (size_t)bb * SEQ * DDIM;
    const _Float16* kb_p = k + bbase;
    const _Float16* vt_p = vT + (size_t)bb * 64 * 512 * 32;  // [kt][dim][key]

    half8 qfrag[16];
    {
      const _Float16* qrow_p = q + bbase + (size_t)(qrow0 + rt * 16 + col) * DDIM;
      #pragma unroll
      for (int s = 0; s < 16; s++)
        qfrag[s] = *(const half8*)(qrow_p + s * 32 + quad * 8);
    }

    float m_run = -INFINITY, l_run = 0.f;
    f32x4 o[4][4];
    #pragma unroll
    for (int a = 0; a < 4; a++)
      #pragma unroll
      for (int b2 = 0; b2 < 4; b2++) o[a][b2] = (f32x4)(0.f);

    // prologue: DMA K tile h + V tile h into buf 0 (8 vmem ops/thread)
    #pragma unroll
    for (int i = 0; i < 4; i++)
      gld_lds16(kb_p + (size_t)(h * 32 + w * 4 + i) * DDIM + lane * 8,
                &Ksh[0][w * 4 + i][0]);
    {
      const _Float16* vtile = vt_p + (size_t)h * 512 * 32;
      #pragma unroll
      for (int i = 0; i < 4; i++) {
        int r = w * 64 + i * 16 + vrl;
        int su = vu ^ ((r >> 1) & 3);
        gld_lds16(vtile + (size_t)r * 32 + su * 8, &VtL[0][w * 64 + i * 16][0]);
      }
    }

    for (int t = 0; t < nT; t++) {
      const int cur = t & 1, nxt = cur ^ 1;
      const int kb0 = (2 * t + h) * 32;

      // issue next tile's DMA into the free buffer (readers done at D(t-1))
      if (t + 1 < nT) {
        const int kb1 = kb0 + 64;
        #pragma unroll
        for (int i = 0; i < 4; i++)
          gld_lds16(kb_p + (size_t)(kb1 + w * 4 + i) * DDIM + lane * 8,
                    &Ksh[nxt][w * 4 + i][0]);
        const _Float16* vtile = vt_p + (size_t)(2 * t + h + 2) * 512 * 32;
        #pragma unroll
        for (int i = 0; i < 4; i++) {
          int r = w * 64 + i * 16 + vrl;
          int su = vu ^ ((r >> 1) & 3);
          gld_lds16(vtile + (size_t)r * 32 + su * 8, &VtL[nxt][w * 64 + i * 16][0]);
        }
      }
      // A: wait tile t's DMA (counted — t+1's 8 ops may stay in flight),
      //    then barrier so ALL waves' tile-t data is in LDS.
      if (t + 1 < nT) { VM8(); } else { VM0(); }
      BAR();
      __builtin_amdgcn_sched_barrier(0);   // pin: no hoist of Ksh/VtL reads

      // ---- scores ----
      {
        f32x4 c = (f32x4)(0.f);
        __builtin_amdgcn_s_setprio(1);
        #pragma unroll
        for (int s = 0; s < 16; s++) {
          half8 b = *(const half8*)&Ksh[cur][kh * 16 + col][s * 32 + quad * 8];
          c = __builtin_amdgcn_mfma_f32_16x16x32_f16(qfrag[s], b, c, 0, 0, 0);
        }
        __builtin_amdgcn_s_setprio(0);
        #pragma unroll
        for (int reg = 0; reg < 4; reg++)
          PsS[(rt * 16 + quad * 4 + reg) * 33 + kh * 16 + col] = c[reg];
      }
      LGKM0(); BAR();    // B: scores visible (no vmcnt drain)

      // ---- softmax ----
      {
        const int qrow = qrow0 + smrow;
        float sv[4];
        #pragma unroll
        for (int i = 0; i < 4; i++) {
          float s = PsS[smrow * 33 + sme * 4 + i] * FSCALE;
          if (kb0 + sme * 4 + i > qrow) s = -INFINITY;
          sv[i] = s;
        }
        float mx = fmaxf(fmaxf(sv[0], sv[1]), fmaxf(sv[2], sv[3]));
        #pragma unroll
        for (int m = 1; m <= 4; m <<= 1) mx = fmaxf(mx, __shfl_xor(mx, m, 64));
        float mn = fmaxf(m_run, mx);
        float mnc = fmaxf(mn, -1e30f);     // guard fully-masked rows
        float al = __expf(m_run - mnc);
        half4 p4;
        float rs = 0.f;
        #pragma unroll
        for (int i = 0; i < 4; i++) {
          float p = __expf(sv[i] - mnc);
          rs += p;
          p4[i] = (_Float16)p;
        }
        #pragma unroll
        for (int m = 1; m <= 4; m <<= 1) rs += __shfl_xor(rs, m, 64);
        l_run = l_run * al + rs;
        m_run = mn;
        *(half4*)&Pf[smrow * 40 + sme * 4] = p4;
        if (sme == 0) alpha_l[smrow] = al;
      }
      LGKM0(); BAR();    // C: Pf + alpha visible (no vmcnt drain)

      // ---- PV ----
      {
        half8 ap[4];
        f32x4 af[4];
        #pragma unroll
        for (int r2 = 0; r2 < 4; r2++) {
          ap[r2] = *(const half8*)&Pf[(r2 * 16 + col) * 40 + quad * 8];
          af[r2] = *(const f32x4*)&alpha_l[r2 * 16 + quad * 4];
        }
        #pragma unroll
        for (int r2 = 0; r2 < 4; r2++)
          #pragma unroll
          for (int ct = 0; ct < 4; ct++)
            o[r2][ct] *= af[r2];
        __builtin_amdgcn_s_setprio(1);
        #pragma unroll
        for (int ct = 0; ct < 4; ct++) {
          int R = d0 + ct * 16 + col;
          int ur = quad ^ ((R >> 1) & 3);
          half8 bv = *(const half8*)&VtL[cur][R][ur * 8];
          #pragma unroll
          for (int r2 = 0; r2 < 4; r2++)
            o[r2][ct] = __builtin_amdgcn_mfma_f32_16x16x32_f16(ap[r2], bv, o[r2][ct], 0, 0, 0);
        }
        __builtin_amdgcn_s_setprio(0);
      }
      LGKM0(); BAR();    // D: all LDS reads of buf cur done -> reusable
    }

    // ---- epilogue: write unnormalized partials (f16, nontemporal) + m/l ----
    if (sme == 0) {
      pm[slot * 64 + smrow] = m_run;
      pl[slot * 64 + smrow] = l_run;
    }
    {
      _Float16* pob = po + (size_t)slot * 64 * 512;
      #pragma unroll
      for (int r2 = 0; r2 < 4; r2++) {
        #pragma unroll
        for (int ct = 0; ct < 4; ct++) {
          #pragma unroll
          for (int e = 0; e < 4; e++) {
            __builtin_nontemporal_store(
                (_Float16)o[r2][ct][e],
                &pob[(size_t)(r2 * 16 + quad * 4 + e) * 512 + d0 + ct * 16 + col]);
          }
        }
      }
    }
  }
}

// ---------------------------------------------------------------------------
// 5. split-K merge: out = (w0*o0 + w1*o1) / (w0*l0 + w1*l1). grid (32,8),
//    64-row q-tiles, po f16 NT loads. (round-1 exact — bench-verified)
// ---------------------------------------------------------------------------
__global__ __launch_bounds__(256) void merge_kernel(
    const _Float16* __restrict__ po, const float* __restrict__ pm,
    const float* __restrict__ pl, float* __restrict__ out) {
  __shared__ float w0s[64], w1s[64], dns[64];
  const int tid = threadIdx.x;
  const int qt = blockIdx.x, b = blockIdx.y;
  const int slot0 = (qt * 8 + b) * 2;
  const int slot1 = slot0 + 1;

  if (tid < 64) {
    float m0 = pm[slot0 * 64 + tid], m1 = pm[slot1 * 64 + tid];
    float l0 = pl[slot0 * 64 + tid], l1 = pl[slot1 * 64 + tid];
    float ms = fmaxf(m0, m1);                 // finite: slot0 has diagonal keys
    float a0 = __expf(m0 - ms);               // exp(-inf - finite) = 0 ok
    float a1 = __expf(m1 - ms);
    w0s[tid] = a0;
    w1s[tid] = a1;
    dns[tid] = 1.0f / (a0 * l0 + a1 * l1);
  }
  __syncthreads();

  const half8* p0 = (const half8*)(po + (size_t)slot0 * 64 * 512);
  const half8* p1 = (const half8*)(po + (size_t)slot1 * 64 * 512);
  f32x4* op = (f32x4*)(out + ((size_t)b * SEQ + qt * 64) * 512);
  #pragma unroll 4
  for (int j = 0; j < 16; j++) {
    int e = j * 256 + tid;          // half8 units, row-major 64x512
    int row = e >> 6;               // 64 units per row
    half8 a = __builtin_nontemporal_load(p0 + e);
    half8 c = __builtin_nontemporal_load(p1 + e);
    float w0 = w0s[row], w1 = w1s[row], dn = dns[row];
    f32x4 r0, r1;
    #pragma unroll
    for (int u = 0; u < 4; u++) r0[u] = ((float)a[u] * w0 + (float)c[u] * w1) * dn;
    #pragma unroll
    for (int u = 0; u < 4; u++) r1[u] = ((float)a[4 + u] * w0 + (float)c[4 + u] * w1) * dn;
    op[e * 2]     = r0;
    op[e * 2 + 1] = r1;
  }
}

// ---------------------------------------------------------------------------
extern "C" void kernel_launch(void* const* d_in, const int* in_sizes, int n_in,
                              void* d_out, int out_size, void* d_ws, size_t ws_size,
                              hipStream_t stream) {
  const float* x  = (const float*)d_in[0];
  const float* Wq = (const float*)d_in[1];
  const float* Wk = (const float*)d_in[2];
  const float* Wv = (const float*)d_in[3];
  float* out = (float*)d_out;
  char* ws = (char*)d_ws;

  float* mw  = (float*)(ws + OFF_M);
  int*   wp  = (int*)(ws + OFF_WP);
  int*   xq  = (int*)(ws + OFF_XQ);
  float* sx  = (float*)(ws + OFF_SX);
  _Float16* qkv = (_Float16*)(ws + OFF_QKV);
  _Float16* qf  = qkv;
  _Float16* kf  = qkv + (size_t)NROW * DDIM;
  _Float16* vTf = qkv + 2 * (size_t)NROW * DDIM;
  _Float16* po = (_Float16*)(ws + OFF_PO);
  float* pm = (float*)(ws + OFF_PM);
  float* pl = (float*)(ws + OFF_PL);

  hipMemsetAsync(mw, 0, 16, stream);
  prep_kernel<<<4192, 256, 0, stream>>>(Wq, Wk, Wv, mw, x, xq, sx);
  wquant_kernel<<<768, 256, 0, stream>>>(Wq, Wk, Wv, mw, wp);
  qkv_gemm_kernel<<<dim3(256, 3), 256, 0, stream>>>(xq, wp, sx, mw, qkv);
  flash_kernel<<<dim3(256), 512, 0, stream>>>(qf, kf, vTf, po, pm, pl);
  merge_kernel<<<dim3(32, 8), 256, 0, stream>>>(po, pm, pl, out);
}

// Round 12
// 213.566 us; speedup vs baseline: 1.0203x; 1.0203x over previous
//
#include <hip/hip_runtime.h>
#include <cstdint>
#include <cstddef>

// Problem shape (fixed by setup_inputs): B=8, S=2048, D=512. All tensors f32.
#define BATCH 8
#define SEQ   2048
#define DDIM  512
#define NROW  (BATCH*SEQ)          // 16384 token rows
#define KPACK (DDIM/4)             // 128 packed int32 per row
#define EPSQ  1e-5f
#define FSCALE 0.35355339059327373f  // 8 ** -0.5

typedef _Float16 half8 __attribute__((ext_vector_type(8)));
typedef _Float16 half4 __attribute__((ext_vector_type(4)));
typedef float    f32x4 __attribute__((ext_vector_type(4)));
typedef int      i32x4 __attribute__((ext_vector_type(4)));

// Workspace layout (bytes)
static constexpr size_t OFF_M   = 0;                                   // 3 floats abs-sum
static constexpr size_t OFF_WP  = 256;                                 // 3*512*128 int32 (col-major)
static constexpr size_t OFF_XQ  = OFF_WP + (size_t)3*KPACK*DDIM*4;     // 16384*128 int32
static constexpr size_t OFF_SX  = OFF_XQ + (size_t)NROW*KPACK*4;       // 16384 f32
static constexpr size_t OFF_QKV = OFF_SX + (size_t)NROW*4;             // 3*16384*512 f16
static constexpr size_t OFF_PO  = OFF_QKV + (size_t)3*NROW*DDIM*2;     // 1024 slots * 32 rows * 512 f16
static constexpr size_t OFF_PM  = OFF_PO + (size_t)512*64*512*4;       // 1024*32 f32 m
static constexpr size_t OFF_PL  = OFF_PM + (size_t)1024*32*4;          // 1024*32 f32 l

__device__ __forceinline__ int q8(float v, float s) {
  int i = (int)rintf(v * s);
  i = i < -128 ? -128 : (i > 127 ? 127 : i);
  return i & 0xff;
}

// async global->LDS DMA, 16B per lane; lds dest = wave-uniform base + lane*16
__device__ __forceinline__ void gld_lds16(const _Float16* g, _Float16* l) {
  __builtin_amdgcn_global_load_lds(
      (const __attribute__((address_space(1))) void*)g,
      (__attribute__((address_space(3))) void*)l, 16, 0, 0);
}

// ---------------------------------------------------------------------------
// 1. FUSED prep: blocks 0..95 = weight abs-sum (wsum, 32 blocks x 3 mats);
//    blocks 96..4191 = per-token int8 absmax quantization (aquant).
//    Both bodies byte-identical to the bench-verified standalone kernels
//    (disjoint inputs/outputs, no ordering dependence) — one dispatch
//    instead of two, and the small wsum hides under aquant.
// ---------------------------------------------------------------------------
__global__ __launch_bounds__(256) void prep_kernel(
    const float* __restrict__ Wq, const float* __restrict__ Wk,
    const float* __restrict__ Wv, float* __restrict__ mw,
    const float* __restrict__ x, int* __restrict__ xq,
    float* __restrict__ sx) {
  if (blockIdx.x < 96) {
    // ---- wsum body (grid was (32,3)): mat = bid/32, bx = bid%32 ----
    const int mat = blockIdx.x >> 5;
    const int bx  = blockIdx.x & 31;
    const float* W = mat == 0 ? Wq : (mat == 1 ? Wk : Wv);
    __shared__ float red[256];
    const float4* p = (const float4*)(W + bx * 8192);
    float s = 0.f;
    #pragma unroll
    for (int i = 0; i < 8; i++) {
      float4 a = p[i * 256 + threadIdx.x];
      s += fabsf(a.x) + fabsf(a.y) + fabsf(a.z) + fabsf(a.w);
    }
    red[threadIdx.x] = s;
    __syncthreads();
    for (int w = 128; w > 0; w >>= 1) {
      if ((int)threadIdx.x < w) red[threadIdx.x] += red[threadIdx.x + w];
      __syncthreads();
    }
    if (threadIdx.x == 0) atomicAdd(&mw[mat], red[0]);
  } else {
    // ---- aquant body (grid was 4096): one wave per 512-elem row ----
    int wid = threadIdx.x >> 6, lane = threadIdx.x & 63;
    int row = (blockIdx.x - 96) * 4 + wid;
    const float* xr = x + (size_t)row * DDIM;
    float4 a = ((const float4*)xr)[lane];        // k = 4*lane .. +3
    float4 b = ((const float4*)xr)[64 + lane];   // k = 256+4*lane .. +3
    float amax = fmaxf(fmaxf(fmaxf(fabsf(a.x), fabsf(a.y)), fmaxf(fabsf(a.z), fabsf(a.w))),
                       fmaxf(fmaxf(fabsf(b.x), fabsf(b.y)), fmaxf(fabsf(b.z), fabsf(b.w))));
    for (int off = 32; off > 0; off >>= 1) amax = fmaxf(amax, __shfl_xor(amax, off, 64));
    float aa = fmaxf(amax, EPSQ);
    float scale = 127.0f / aa;
    int p0 = q8(a.x, scale) | (q8(a.y, scale) << 8) | (q8(a.z, scale) << 16) | (q8(a.w, scale) << 24);
    int p1 = q8(b.x, scale) | (q8(b.y, scale) << 8) | (q8(b.z, scale) << 16) | (q8(b.w, scale) << 24);
    xq[(size_t)row * KPACK + lane]      = p0;    // k4 = lane
    xq[(size_t)row * KPACK + 64 + lane] = p1;    // k4 = 64+lane
    if (lane == 0) sx[row] = aa * (1.0f / 127.0f);
  }
}

// ---------------------------------------------------------------------------
// 2. ternary-quantize weights, packed COL-major: wp[mat][o][k4]. grid 768x256.
// ---------------------------------------------------------------------------
__global__ __launch_bounds__(256) void wquant_kernel(
    const float* __restrict__ Wq, const float* __restrict__ Wk,
    const float* __restrict__ Wv, const float* __restrict__ mw,
    int* __restrict__ wp) {
  int idx = blockIdx.x * 256 + threadIdx.x;   // 0 .. 196607
  int mat = idx >> 16;
  int local = idx & 0xFFFF;
  int o  = local >> 7;       // 0..511
  int k4 = local & 127;      // 0..127
  const float* W = mat == 0 ? Wq : (mat == 1 ? Wk : Wv);
  float mean = mw[mat] * (1.0f / 262144.0f);
  float scale = 1.0f / fmaxf(mean, EPSQ);
  float4 w4 = *(const float4*)(W + (size_t)o * DDIM + k4 * 4);
  int t0 = (int)rintf(w4.x * scale); t0 = t0 < -1 ? -1 : (t0 > 1 ? 1 : t0);
  int t1 = (int)rintf(w4.y * scale); t1 = t1 < -1 ? -1 : (t1 > 1 ? 1 : t1);
  int t2 = (int)rintf(w4.z * scale); t2 = t2 < -1 ? -1 : (t2 > 1 ? 1 : t2);
  int t3 = (int)rintf(w4.w * scale); t3 = t3 < -1 ? -1 : (t3 > 1 ? 1 : t3);
  int packed = (t0 & 0xff) | ((t1 & 0xff) << 8) | ((t2 & 0xff) << 16) | ((t3 & 0xff) << 24);
  wp[((size_t)mat * DDIM + o) * KPACK + k4] = packed;
}

// ---------------------------------------------------------------------------
// 3. int8 x ternary GEMM via i8 MFMA. grid (256, 3), block 256.
//    (round-6 exact — bench-verified best: A staged once, 8 column tiles,
//    B-tile register prefetch hidden under MFMA. At its ~90 MB memory
//    roofline; store-coalescing (r7) and traffic cuts (r6) were neutral.)
// ---------------------------------------------------------------------------
__global__ __launch_bounds__(256, 2) void qkv_gemm_kernel(
    const int* __restrict__ xq, const int* __restrict__ wp,
    const float* __restrict__ sx, const float* __restrict__ mw,
    _Float16* __restrict__ qkv) {
  __shared__ __align__(16) int xs[64][132];   // A-tile, padded
  __shared__ __align__(16) int bs[64][132];   // B-tile (col-major), padded
  __shared__ float sxs[64];

  const int tid  = threadIdx.x;
  const int w    = tid >> 6;
  const int lane = tid & 63;
  const int quad = lane >> 4;
  const int col  = lane & 15;

  const int r0g = blockIdx.x * 64;      // row block
  const int mat = blockIdx.y;

  // stage A once (verified scalar path, padded = conflict-free)
  {
    const i32x4* src = (const i32x4*)(xq + (size_t)r0g * KPACK);
    #pragma unroll
    for (int i = 0; i < 8; i++) {
      int e = i * 256 + tid;
      int row = e >> 5, u = e & 31;
      *(i32x4*)&xs[row][u * 4] = src[e];
    }
  }
  if (tid < 64) sxs[tid] = sx[r0g + tid];

  const float mval = fmaxf(mw[mat] * (1.0f / 262144.0f), EPSQ);

  // prefetch B tile 0 into registers
  i32x4 breg[8];
  {
    const i32x4* src = (const i32x4*)(wp + (size_t)mat * DDIM * KPACK);
    #pragma unroll
    for (int i = 0; i < 8; i++) breg[i] = src[i * 256 + tid];
  }

  for (int nb = 0; nb < 8; nb++) {
    const int n0 = nb * 64;
    __syncthreads();                    // prev round's bs reads done (xs ready, 1st iter)
    #pragma unroll
    for (int i = 0; i < 8; i++) {
      int e = i * 256 + tid;
      int c = e >> 5, u = e & 31;
      *(i32x4*)&bs[c][u * 4] = breg[i];
    }
    __syncthreads();                    // bs ready
    if (nb + 1 < 8) {                   // prefetch next B tile (hidden by MFMA)
      const i32x4* src = (const i32x4*)(wp + ((size_t)mat * DDIM + n0 + 64) * KPACK);
      #pragma unroll
      for (int i = 0; i < 8; i++) breg[i] = src[i * 256 + tid];
    }

    i32x4 acc[4];
    #pragma unroll
    for (int rt = 0; rt < 4; rt++) acc[rt] = (i32x4)(0);

    #pragma unroll
    for (int s = 0; s < 8; s++) {
      i32x4 bf = *(const i32x4*)&bs[w * 16 + col][s * 16 + quad * 4];
      #pragma unroll
      for (int rt = 0; rt < 4; rt++) {
        i32x4 af = *(const i32x4*)&xs[rt * 16 + col][s * 16 + quad * 4];
        acc[rt] = __builtin_amdgcn_mfma_i32_16x16x64_i8(af, bf, acc[rt], 0, 0, 0);
      }
    }

    const int nw = n0 + w * 16 + col;   // this lane's output column

    if (mat < 2) {
      _Float16* outb = qkv + (size_t)mat * NROW * DDIM;
      #pragma unroll
      for (int rt = 0; rt < 4; rt++) {
        #pragma unroll
        for (int reg = 0; reg < 4; reg++) {
          int rowl = rt * 16 + quad * 4 + reg;
          outb[(size_t)(r0g + rowl) * DDIM + nw] =
              (_Float16)((float)acc[rt][reg] * sxs[rowl] * mval);
        }
      }
    } else {
      _Float16* vT = qkv + (size_t)2 * NROW * DDIM;
      #pragma unroll
      for (int rt = 0; rt < 4; rt++) {
        half4 hv;
        #pragma unroll
        for (int reg = 0; reg < 4; reg++) {
          int rowl = rt * 16 + quad * 4 + reg;
          hv[reg] = (_Float16)((float)acc[rt][reg] * sxs[rowl] * mval);
        }
        int r = r0g + rt * 16 + quad * 4;        // first of 4 consecutive keys
        int b = r >> 11, kt = (r & 2047) >> 5, kin = r & 31;
        *(half4*)(vT + ((((size_t)b * 64 + kt) * 512 + nw) * 32 + kin)) = hv;
      }
    }
  }
}

// ---------------------------------------------------------------------------
// 4. f16 MFMA flash attention (round-3 EXACT, bench-verified 90-94 us).
//    QBLK=32, 256-thread blocks (4 waves), grid 1024 (64 q-tiles x 8 batches
//    x 2 key parities), 2 blocks/CU (LDS 72,960 B), batch->XCD pinned.
//    Session-verified invariants:
//    - NO device-scope fences / cross-block tails (r5+r8: __threadfence here
//      destroys per-XCD L2 residency, flash 90 -> 340 us).
//    - Counted-vmcnt/raw-barrier schedule (r11) is correct but NEUTRAL: the
//      floor is the 4-phase barrier chain, not the DMA drain.
//    - K-read swizzle is a null-op (conflicts live in PsS/Pf, r5 counter).
// ---------------------------------------------------------------------------
__global__ __launch_bounds__(256, 2) void flash_kernel(
    const _Float16* __restrict__ q, const _Float16* __restrict__ k,
    const _Float16* __restrict__ vT, _Float16* __restrict__ po,
    float* __restrict__ pm, float* __restrict__ pl) {
  __shared__ __align__(16) _Float16 Ksh[32][520];   // 33,280 B (DMA rows)
  __shared__ __align__(16) _Float16 VtL[512][32];   // 32,768 B (DMA, swizzled)
  __shared__ __align__(16) float    PsS[32 * 33];   //  4,224 B raw scores
  __shared__ __align__(16) _Float16 Pf[32 * 40];    //  2,560 B probabilities
  __shared__ float alpha_l[32];                     //    128 B
  // total 72,960 B -> 2 blocks/CU

  const int tid  = threadIdx.x;
  const int w    = tid >> 6;        // 0..3
  const int lane = tid & 63;
  const int quad = lane >> 4;
  const int col  = lane & 15;
  const int rt   = w & 1;           // score row-tile 0..1
  const int kh   = w >> 1;          // score key-half 0..1
  const int smrow = tid >> 3;       // softmax row 0..31
  const int sme   = tid & 7;        // softmax key group 0..7
  const int d0  = w * 128;          // PV dim slice (128 dims per wave)

  const int vrl = lane >> 2;        // V-DMA row-in-group 0..15
  const int vu  = lane & 3;         // V-DMA 16B unit 0..3

  const int bb = blockIdx.x & 7;    // batch == XCD id (L2 pinning; 1024%8==0)
  const int r  = blockIdx.x >> 3;   // 0..127
  const int h  = r < 64 ? 0 : 1;    // key-tile parity
  const int qt = r < 64 ? r : 127 - r;   // q-tile 0..63 (32 rows each)
  // key tiles kt (32 keys) with kt <= qt and kt%2 == h:
  const int nT = h == 0 ? (qt / 2 + 1) : ((qt + 1) / 2);
  const int slot = (qt * 8 + bb) * 2 + h;

  const int qrow0 = qt * 32;
  const size_t bbase = (size_t)bb * SEQ * DDIM;
  const _Float16* kb_p = k + bbase;
  const _Float16* vt_p = vT + (size_t)bb * 64 * 512 * 32;  // [kt][dim][key]

  half8 qfrag[16];
  {
    const _Float16* qrow_p = q + bbase + (size_t)(qrow0 + rt * 16 + col) * DDIM;
    #pragma unroll
    for (int s = 0; s < 16; s++)
      qfrag[s] = *(const half8*)(qrow_p + s * 32 + quad * 8);
  }

  float m_run = -INFINITY, l_run = 0.f;
  f32x4 o[2][8];
  #pragma unroll
  for (int a = 0; a < 2; a++)
    #pragma unroll
    for (int b2 = 0; b2 < 8; b2++) o[a][b2] = (f32x4)(0.f);

  for (int t = 0; t < nT; t++) {
    const int kt  = 2 * t + h;          // parity-strided key tile
    const int kb0 = kt * 32;

    // ---- DMA K + V for THIS tile (single-buffered). 4 waves x 8 rows/groups.
    #pragma unroll
    for (int i = 0; i < 8; i++)
      gld_lds16(kb_p + (size_t)(kb0 + w * 8 + i) * DDIM + lane * 8,
                &Ksh[w * 8 + i][0]);
    {
      const _Float16* vtile = vt_p + (size_t)kt * 512 * 32;
      #pragma unroll
      for (int i = 0; i < 8; i++) {
        int rr = w * 128 + i * 16 + vrl;
        int su = vu ^ ((rr >> 1) & 3);
        gld_lds16(vtile + (size_t)rr * 32 + su * 8, &VtL[w * 128 + i * 16][0]);
      }
    }
    __syncthreads();   // A: drains DMA -> K,V visible

    // ---- scores (32x32 tile; wave (rt,kh) does a 16x16 quadrant) ----
    {
      f32x4 c = (f32x4)(0.f);
      __builtin_amdgcn_s_setprio(1);
      #pragma unroll
      for (int s = 0; s < 16; s++) {
        half8 b = *(const half8*)&Ksh[kh * 16 + col][s * 32 + quad * 8];
        c = __builtin_amdgcn_mfma_f32_16x16x32_f16(qfrag[s], b, c, 0, 0, 0);
      }
      __builtin_amdgcn_s_setprio(0);
      #pragma unroll
      for (int reg = 0; reg < 4; reg++)
        PsS[(rt * 16 + quad * 4 + reg) * 33 + kh * 16 + col] = c[reg];
    }
    __syncthreads();   // B: scores ready

    // ---- softmax (32 rows, 8 threads/row) ----
    {
      const int qrow = qrow0 + smrow;
      float sv[4];
      #pragma unroll
      for (int i = 0; i < 4; i++) {
        float s = PsS[smrow * 33 + sme * 4 + i] * FSCALE;
        if (kb0 + sme * 4 + i > qrow) s = -INFINITY;
        sv[i] = s;
      }
      float mx = fmaxf(fmaxf(sv[0], sv[1]), fmaxf(sv[2], sv[3]));
      #pragma unroll
      for (int m = 1; m <= 4; m <<= 1) mx = fmaxf(mx, __shfl_xor(mx, m, 64));
      float mn = fmaxf(m_run, mx);
      float mnc = fmaxf(mn, -1e30f);     // guard fully-masked rows
      float al = __expf(m_run - mnc);
      half4 p4;
      float rs = 0.f;
      #pragma unroll
      for (int i = 0; i < 4; i++) {
        float p = __expf(sv[i] - mnc);
        rs += p;
        p4[i] = (_Float16)p;
      }
      #pragma unroll
      for (int m = 1; m <= 4; m <<= 1) rs += __shfl_xor(rs, m, 64);
      l_run = l_run * al + rs;
      m_run = mn;
      *(half4*)&Pf[smrow * 40 + sme * 4] = p4;
      if (sme == 0) alpha_l[smrow] = al;
    }
    __syncthreads();   // C: Pf + alpha ready

    // ---- PV (each wave: 32 rows x 128 dims) ----
    {
      half8 ap[2];
      f32x4 af[2];
      #pragma unroll
      for (int r2 = 0; r2 < 2; r2++) {
        ap[r2] = *(const half8*)&Pf[(r2 * 16 + col) * 40 + quad * 8];
        af[r2] = *(const f32x4*)&alpha_l[r2 * 16 + quad * 4];
      }
      #pragma unroll
      for (int r2 = 0; r2 < 2; r2++)
        #pragma unroll
        for (int ct = 0; ct < 8; ct++)
          o[r2][ct] *= af[r2];
      __builtin_amdgcn_s_setprio(1);
      #pragma unroll
      for (int ct = 0; ct < 8; ct++) {
        int R = d0 + ct * 16 + col;
        int ur = quad ^ ((R >> 1) & 3);
        half8 bv = *(const half8*)&VtL[R][ur * 8];
        #pragma unroll
        for (int r2 = 0; r2 < 2; r2++)
          o[r2][ct] = __builtin_amdgcn_mfma_f32_16x16x32_f16(ap[r2], bv, o[r2][ct], 0, 0, 0);
      }
      __builtin_amdgcn_s_setprio(0);
    }
    __syncthreads();   // D: all LDS reads done before next tile's DMA
  }

  // ---- epilogue: write unnormalized partials (f16, nontemporal) + m/l ----
  if (sme == 0) {
    pm[slot * 32 + smrow] = m_run;
    pl[slot * 32 + smrow] = l_run;
  }
  {
    _Float16* pob = po + (size_t)slot * 32 * 512;
    #pragma unroll
    for (int r2 = 0; r2 < 2; r2++) {
      #pragma unroll
      for (int ct = 0; ct < 8; ct++) {
        #pragma unroll
        for (int e = 0; e < 4; e++) {
          __builtin_nontemporal_store(
              (_Float16)o[r2][ct][e],
              &pob[(size_t)(r2 * 16 + quad * 4 + e) * 512 + d0 + ct * 16 + col]);
        }
      }
    }
  }
}

// ---------------------------------------------------------------------------
// 5. split-K merge: out = (w0*o0 + w1*o1) / (w0*l0 + w1*l1). grid (64,8),
//    32-row q-tiles. po f16, nontemporal loads. (round-3 exact; at its
//    ~96 MB memory roofline)
// ---------------------------------------------------------------------------
__global__ __launch_bounds__(256) void merge_kernel(
    const _Float16* __restrict__ po, const float* __restrict__ pm,
    const float* __restrict__ pl, float* __restrict__ out) {
  __shared__ float w0s[32], w1s[32], dns[32];
  const int tid = threadIdx.x;
  const int qt = blockIdx.x, b = blockIdx.y;
  const int slot0 = (qt * 8 + b) * 2;
  const int slot1 = slot0 + 1;

  if (tid < 32) {
    float m0 = pm[slot0 * 32 + tid], m1 = pm[slot1 * 32 + tid];
    float l0 = pl[slot0 * 32 + tid], l1 = pl[slot1 * 32 + tid];
    float ms = fmaxf(m0, m1);                 // finite: slot0 has diagonal keys
    float a0 = __expf(m0 - ms);               // exp(-inf - finite) = 0 ok
    float a1 = __expf(m1 - ms);
    w0s[tid] = a0;
    w1s[tid] = a1;
    dns[tid] = 1.0f / (a0 * l0 + a1 * l1);
  }
  __syncthreads();

  const half8* p0 = (const half8*)(po + (size_t)slot0 * 32 * 512);
  const half8* p1 = (const half8*)(po + (size_t)slot1 * 32 * 512);
  f32x4* op = (f32x4*)(out + ((size_t)b * SEQ + qt * 32) * 512);
  #pragma unroll 4
  for (int j = 0; j < 8; j++) {
    int e = j * 256 + tid;          // half8 units, row-major 32x512
    int row = e >> 6;               // 64 units per row
    half8 a = __builtin_nontemporal_load(p0 + e);
    half8 c = __builtin_nontemporal_load(p1 + e);
    float w0 = w0s[row], w1 = w1s[row], dn = dns[row];
    f32x4 r0, r1;
    #pragma unroll
    for (int u = 0; u < 4; u++) r0[u] = ((float)a[u] * w0 + (float)c[u] * w1) * dn;
    #pragma unroll
    for (int u = 0; u < 4; u++) r1[u] = ((float)a[4 + u] * w0 + (float)c[4 + u] * w1) * dn;
    op[e * 2]     = r0;
    op[e * 2 + 1] = r1;
  }
}

// ---------------------------------------------------------------------------
extern "C" void kernel_launch(void* const* d_in, const int* in_sizes, int n_in,
                              void* d_out, int out_size, void* d_ws, size_t ws_size,
                              hipStream_t stream) {
  const float* x  = (const float*)d_in[0];
  const float* Wq = (const float*)d_in[1];
  const float* Wk = (const float*)d_in[2];
  const float* Wv = (const float*)d_in[3];
  float* out = (float*)d_out;
  char* ws = (char*)d_ws;

  float* mw  = (float*)(ws + OFF_M);
  int*   wp  = (int*)(ws + OFF_WP);
  int*   xq  = (int*)(ws + OFF_XQ);
  float* sx  = (float*)(ws + OFF_SX);
  _Float16* qkv = (_Float16*)(ws + OFF_QKV);
  _Float16* qf  = qkv;
  _Float16* kf  = qkv + (size_t)NROW * DDIM;
  _Float16* vTf = qkv + 2 * (size_t)NROW * DDIM;
  _Float16* po = (_Float16*)(ws + OFF_PO);
  float* pm = (float*)(ws + OFF_PM);
  float* pl = (float*)(ws + OFF_PL);

  hipMemsetAsync(mw, 0, 16, stream);
  prep_kernel<<<4192, 256, 0, stream>>>(Wq, Wk, Wv, mw, x, xq, sx);
  wquant_kernel<<<768, 256, 0, stream>>>(Wq, Wk, Wv, mw, wp);
  qkv_gemm_kernel<<<dim3(256, 3), 256, 0, stream>>>(xq, wp, sx, mw, qkv);
  flash_kernel<<<dim3(1024), 256, 0, stream>>>(qf, kf, vTf, po, pm, pl);
  merge_kernel<<<dim3(64, 8), 256, 0, stream>>>(po, pm, pl, out);
}